// Round 7
// baseline (69.402 us; speedup 1.0000x reference)
//
#include <hip/hip_runtime.h>
#include <cstdint>
#include <cstddef>

// Problem constants (reference: N=8192, C=1000, A=768)
#define N_SAMPLES 8192
#define N_CLASSES 1000
#define C_PAD     1024
#define A_DIM     768
#define K_DIM     1536   // 2*A  (concatenated [u ; v] / [W^2 ; W])
#define BM 256
#define BN 128
#define BK 64
#define NT (K_DIM / BK)  // 24 K-steps

typedef __attribute__((ext_vector_type(8))) __bf16 bf16x8;
typedef __attribute__((ext_vector_type(4))) __bf16 bf16x4;
typedef __attribute__((ext_vector_type(4))) float  f32x4;

#define WAIT_VM(N) do { asm volatile("s_waitcnt vmcnt(" #N ")" ::: "memory"); \
                        __builtin_amdgcn_sched_barrier(0); } while (0)
#define WAIT_LGKM0 do { asm volatile("s_waitcnt lgkmcnt(0)" ::: "memory"); \
                        __builtin_amdgcn_sched_barrier(0); } while (0)

// ---- merged prep: waves 0..8191 build UV rows; waves 8192..9215 build Wcat --
// UV[n][a] = cv_k ; UV[n][768+a] = -2*Wk*cv_k   (t3 dropped: row-constant
// shift cancels exactly in log-softmax). Wcat[c][a]=W^2 ; Wcat[c][768+a]=W.
__global__ void prep(const float* __restrict__ W, const float* __restrict__ CV,
                     const int* __restrict__ labels,
                     __bf16* __restrict__ UV, __bf16* __restrict__ Wcat) {
    int gw   = (blockIdx.x * blockDim.x + threadIdx.x) >> 6;
    int lane = threadIdx.x & 63;
    if (gw < N_SAMPLES) {
        int lab = labels[gw];
        const float* wr = W  + (size_t)lab * A_DIM;
        const float* cr = CV + (size_t)lab * A_DIM;
        #pragma unroll
        for (int p = 0; p < 3; ++p) {
            int a = p * 256 + lane * 4;
            f32x4 wk = *reinterpret_cast<const f32x4*>(wr + a);
            f32x4 cv = *reinterpret_cast<const f32x4*>(cr + a);
            bf16x4 u, v;
            #pragma unroll
            for (int j = 0; j < 4; ++j) {
                u[j] = (__bf16)cv[j];
                v[j] = (__bf16)(-2.0f * wk[j] * cv[j]);
            }
            *reinterpret_cast<bf16x4*>(UV + (size_t)gw * K_DIM + a)         = u;
            *reinterpret_cast<bf16x4*>(UV + (size_t)gw * K_DIM + A_DIM + a) = v;
        }
    } else {
        int c = gw - N_SAMPLES;          // 0..1023
        if (c < N_CLASSES) {
            #pragma unroll
            for (int p = 0; p < 3; ++p) {
                int a = p * 256 + lane * 4;
                f32x4 w = *reinterpret_cast<const f32x4*>(W + (size_t)c * A_DIM + a);
                bf16x4 sq, li;
                #pragma unroll
                for (int j = 0; j < 4; ++j) { sq[j] = (__bf16)(w[j] * w[j]); li[j] = (__bf16)w[j]; }
                *reinterpret_cast<bf16x4*>(Wcat + (size_t)c * K_DIM + a)         = sq;
                *reinterpret_cast<bf16x4*>(Wcat + (size_t)c * K_DIM + A_DIM + a) = li;
            }
        } else {
            bf16x4 z = {(__bf16)0.f, (__bf16)0.f, (__bf16)0.f, (__bf16)0.f};
            #pragma unroll
            for (int p = 0; p < 6; ++p)
                *reinterpret_cast<bf16x4*>(Wcat + (size_t)c * K_DIM + p * 256 + lane * 4) = z;
        }
    }
}

// -------- GEMM + fused partial log-softmax --------------------------------
// acc[n][c] = sum_k UV[n,k]*Wcat[c,k] (t1-2t2); f = logits + h*acc.
// Per block (256 rows x 128 cols): per-row (max, expsum) over its 128 cols ->
// partial[colTile][row] (float2); scatter labval[row]=f where col==label[row].
// K-loop identical to R6 (verified): 3-stage pipeline, m201 phase discipline,
// counted vmcnt(6), XOR source-swizzle, XCD-chunked block swizzle.
__global__ __launch_bounds__(512, 2) void gemm_lse(
        const __bf16* __restrict__ UV, const __bf16* __restrict__ Wcat,
        const float* __restrict__ logits, const float* __restrict__ ratiop,
        const int* __restrict__ labels,
        float2* __restrict__ partial, float* __restrict__ labval) {
    __shared__ __align__(16) __bf16 As[3][BM * BK];   // 3 x 32 KB
    __shared__ __align__(16) __bf16 Bs[3][BN * BK];   // 3 x 16 KB
    __shared__ float lsm[2][BM];                      // per-wc row max
    __shared__ float lss[2][BM];                      // per-wc row expsum
    __shared__ int   slab[BM];                        // labels for block rows
    int tid  = threadIdx.x;
    int lane = tid & 63;
    int wave = tid >> 6;
    // XCD-chunked bijective swizzle: 256 blocks, 8 XCDs, 32 blocks/XCD.
    int wgid = (blockIdx.x & 7) * 32 + (blockIdx.x >> 3);
    int rowTile = wgid >> 3;         // 32 row tiles of 256 samples
    int colTile = wgid & 7;          // 8 col tiles of 128 classes
    int rowBase = rowTile * BM;
    int colBase = colTile * BN;
    int wr = wave >> 1;              // 4x2 wave grid, each wave owns 64x64
    int wc = wave & 1;

    f32x4 acc[4][4];
    #pragma unroll
    for (int m = 0; m < 4; ++m)
        #pragma unroll
        for (int n = 0; n < 4; ++n)
            acc[m][n] = (f32x4){0.f, 0.f, 0.f, 0.f};

    auto stageA = [&](int b, int k0) {           // 256x64 A-tile: 4 loads/thread
        #pragma unroll
        for (int i = 0; i < 4; ++i) {
            int lin  = i * 512 + tid;
            int row  = lin >> 3;                 // 0..255
            int scch = (lin & 7) ^ (row & 7);
            int base = i * 512 + (tid & ~63);
            const __bf16* ga = UV + (size_t)(rowBase + row) * K_DIM + k0 + scch * 8;
            __builtin_amdgcn_global_load_lds(
                (const __attribute__((address_space(1))) void*)ga,
                (__attribute__((address_space(3))) void*)((char*)&As[b][0] + (size_t)base * 16),
                16, 0, 0);
        }
    };
    auto stageB = [&](int b, int k0) {           // 128x64 B-tile: 2 loads/thread
        #pragma unroll
        for (int i = 0; i < 2; ++i) {
            int lin  = i * 512 + tid;
            int row  = lin >> 3;                 // 0..127
            int scch = (lin & 7) ^ (row & 7);
            int base = i * 512 + (tid & ~63);
            const __bf16* gb = Wcat + (size_t)(colBase + row) * K_DIM + k0 + scch * 8;
            __builtin_amdgcn_global_load_lds(
                (const __attribute__((address_space(1))) void*)gb,
                (__attribute__((address_space(3))) void*)((char*)&Bs[b][0] + (size_t)base * 16),
                16, 0, 0);
        }
    };
    auto loadFrags = [&](int b, int kk, bf16x8* af, bf16x8* bf) {
        int swch = ((kk * 4 + (lane >> 4)) ^ (lane & 7)) * 8;
        #pragma unroll
        for (int m = 0; m < 4; ++m) {
            int r = wr * 64 + m * 16 + (lane & 15);
            af[m] = *reinterpret_cast<const bf16x8*>(&As[b][r * BK + swch]);
        }
        #pragma unroll
        for (int n = 0; n < 4; ++n) {
            int c = wc * 64 + n * 16 + (lane & 15);
            bf[n] = *reinterpret_cast<const bf16x8*>(&Bs[b][c * BK + swch]);
        }
    };
    auto doMFMA = [&](bf16x8* af, bf16x8* bf) {
        __builtin_amdgcn_s_setprio(1);
        #pragma unroll
        for (int m = 0; m < 4; ++m)
            #pragma unroll
            for (int n = 0; n < 4; ++n)
                acc[m][n] = __builtin_amdgcn_mfma_f32_16x16x32_bf16(
                    af[m], bf[n], acc[m][n], 0, 0, 0);
        __builtin_amdgcn_s_setprio(0);
    };

    // prologue: tiles 0,1 staged; labels for this block's rows -> LDS
    stageA(0, 0);        stageB(0, 0);
    stageA(1, BK);       stageB(1, BK);
    if (tid < BM) slab[tid] = labels[rowBase + tid];
    WAIT_VM(6);
    __builtin_amdgcn_s_barrier();

    for (int kt = 0; kt < NT; ++kt) {
        int bR = kt % 3;
        int bS = (kt + 2) % 3;
        bool st = (kt + 2) < NT;
        int k2 = (kt + 2) * BK;
        bf16x8 af[4], bf[4];
        // ---- phase 0 (kk=0)
        loadFrags(bR, 0, af, bf);
        if (st) stageA(bS, k2);
        __builtin_amdgcn_s_barrier();
        WAIT_LGKM0;
        doMFMA(af, bf);
        __builtin_amdgcn_s_barrier();
        // ---- phase 1 (kk=1)
        loadFrags(bR, 1, af, bf);
        if (st) stageB(bS, k2);
        if (st) { WAIT_VM(6); } else { WAIT_VM(0); }
        __builtin_amdgcn_s_barrier();
        WAIT_LGKM0;
        doMFMA(af, bf);
        __builtin_amdgcn_s_barrier();
    }

    // ---- fused epilogue: f = logits + h*acc; per-row (max,expsum) ----------
    // C/D layout col=lane&15, row=(lane>>4)*4+j [m89/m91]
    float h  = 0.5f * ratiop[0];
    int   g  = lane >> 4;            // 16-lane col-group id
    int   lc = lane & 15;
    #pragma unroll
    for (int m = 0; m < 4; ++m) {
        int lrow0 = wr * 64 + m * 16 + g * 4;    // local row of j=0
        int grow0 = rowBase + lrow0;
        float fv[4][4];                          // [n][j]
        #pragma unroll
        for (int n = 0; n < 4; ++n) {
            int gc = colBase + wc * 64 + n * 16 + lc;
            bool valid = gc < N_CLASSES;
            #pragma unroll
            for (int j = 0; j < 4; ++j) {
                float lg = valid ? logits[(size_t)(grow0 + j) * N_CLASSES + gc] : 0.f;
                fv[n][j] = valid ? lg + h * acc[m][n][j] : -1e30f;
                if (valid && gc == slab[lrow0 + j])
                    labval[grow0 + j] = fv[n][j];
            }
        }
        #pragma unroll
        for (int j = 0; j < 4; ++j) {
            float mx = fmaxf(fmaxf(fv[0][j], fv[1][j]), fmaxf(fv[2][j], fv[3][j]));
            #pragma unroll
            for (int s = 1; s < 16; s <<= 1) mx = fmaxf(mx, __shfl_xor(mx, s));
            float sm = __expf(fv[0][j] - mx) + __expf(fv[1][j] - mx)
                     + __expf(fv[2][j] - mx) + __expf(fv[3][j] - mx);
            #pragma unroll
            for (int s = 1; s < 16; s <<= 1) sm += __shfl_xor(sm, s);
            if (lc == 0) { lsm[wc][lrow0 + j] = mx; lss[wc][lrow0 + j] = sm; }
        }
    }
    __syncthreads();
    // cross-wave (wc=0,1) combine; wc==0 waves own 64 rows each
    if (wc == 0) {
        int lrow = wr * 64 + lane;
        float m0 = lsm[0][lrow], m1 = lsm[1][lrow];
        float M  = fmaxf(m0, m1);
        float S  = lss[0][lrow] * __expf(m0 - M) + lss[1][lrow] * __expf(m1 - M);
        partial[(size_t)colTile * N_SAMPLES + rowBase + lrow] = make_float2(M, S);
    }
}

// ---- combine 8 partials/row -> rowloss; deterministic mean (one block) -----
__global__ void finalize(const float2* __restrict__ partial,
                         const float* __restrict__ labval,
                         float* __restrict__ out) {
    int tid = threadIdx.x;               // 1024 threads
    float accu = 0.f;
    #pragma unroll
    for (int i = 0; i < 8; ++i) {
        int r = i * 1024 + tid;
        float2 p = partial[r];
        float M = p.x, S = p.y;
        #pragma unroll
        for (int b = 1; b < 8; ++b) {
            float2 q = partial[(size_t)b * N_SAMPLES + r];
            float M2 = fmaxf(M, q.x);
            S = S * __expf(M - M2) + q.y * __expf(q.x - M2);
            M = M2;
        }
        accu += M + logf(S) - labval[r];
    }
    #pragma unroll
    for (int s = 32; s > 0; s >>= 1) accu += __shfl_xor(accu, s);
    __shared__ float tmp[16];
    int lane = tid & 63, wv = tid >> 6;
    if (lane == 0) tmp[wv] = accu;
    __syncthreads();
    if (tid == 0) {
        float sum = 0.f;
        #pragma unroll
        for (int w = 0; w < 16; ++w) sum += tmp[w];
        out[0] = sum / (float)N_SAMPLES;
    }
}

extern "C" void kernel_launch(void* const* d_in, const int* in_sizes, int n_in,
                              void* d_out, int out_size, void* d_ws, size_t ws_size,
                              hipStream_t stream) {
    const float* W      = (const float*)d_in[0];   // fc_weight [C, A]
    // d_in[1] = features [N, A] — unused by the reference math
    const float* logits = (const float*)d_in[2];   // [N, C]
    const int*   labels = (const int*)d_in[3];     // [N]
    const float* ratio  = (const float*)d_in[4];   // scalar
    const float* CV     = (const float*)d_in[5];   // cv_matrix [C, A]
    // d_in[6] = manner — unused

    // workspace layout (bytes), total ~28.9 MB
    char* ws = (char*)d_ws;
    __bf16* Wcat    = (__bf16*)(ws + 0);            //  3,145,728 B  [1024][1536] bf16
    __bf16* UV      = (__bf16*)(ws + 3145728);      // 25,165,824 B  [8192][1536] bf16
    float2* partial = (float2*)(ws + 28311552);     //    524,288 B  [8][8192] float2
    float*  labval  = (float*) (ws + 28835840);     //     32,768 B  [8192] f32

    prep<<<(N_SAMPLES + C_PAD) / 4, 256, 0, stream>>>(W, CV, labels, UV, Wcat);
    gemm_lse<<<256, 512, 0, stream>>>(UV, Wcat, logits, ratio, labels, partial, labval);
    finalize<<<1, 1024, 0, stream>>>(partial, labval, (float*)d_out);
}

// Round 8
// 39.414 us; speedup vs baseline: 1.7609x; 1.7609x over previous
//
#include <hip/hip_runtime.h>
#include <cstdint>
#include <cstddef>

// Problem constants (reference: N=8192, C=1000, A=768)
// KEY IDENTITY: sigma2[n,c] = ratio * sum_a (W[c,a]-W[l,a])^2 cv[l,a] depends
// on n only through l = labels[n]. Compute G[l,c] once (1024^2) and gather.
#define N_SAMPLES 8192
#define N_CLASSES 1000
#define C_PAD     1024
#define A_DIM     768
#define K_DIM     1536   // 2*A  (concatenated [u ; v] / [W^2 ; W])
#define BT 64            // G-GEMM tile (64x64)
#define BK 64
#define NT (K_DIM / BK)  // 24 K-steps

typedef __attribute__((ext_vector_type(8))) __bf16 bf16x8;
typedef __attribute__((ext_vector_type(4))) __bf16 bf16x4;
typedef __attribute__((ext_vector_type(4))) float  f32x4;

#define WAIT_VM(N) do { asm volatile("s_waitcnt vmcnt(" #N ")" ::: "memory"); \
                        __builtin_amdgcn_sched_barrier(0); } while (0)
#define WAIT_LGKM0 do { asm volatile("s_waitcnt lgkmcnt(0)" ::: "memory"); \
                        __builtin_amdgcn_sched_barrier(0); } while (0)

// ---- prep: waves 0..1023 build UVc rows; waves 1024..2047 build Wcat rows --
// UVc[l][a] = cv[l,a] ; UVc[l][768+a] = -2*W[l,a]*cv[l,a]  (t3 term is a
// per-row constant shift -> cancels exactly in log-softmax; dropped).
// Wcat[c][a] = W[c,a]^2 ; Wcat[c][768+a] = W[c,a].  Pad rows zeroed.
__global__ void prep(const float* __restrict__ W, const float* __restrict__ CV,
                     __bf16* __restrict__ UVc, __bf16* __restrict__ Wcat) {
    int gw   = (blockIdx.x * blockDim.x + threadIdx.x) >> 6;
    int lane = threadIdx.x & 63;
    bf16x4 z = {(__bf16)0.f, (__bf16)0.f, (__bf16)0.f, (__bf16)0.f};
    if (gw < C_PAD) {
        int l = gw;
        if (l < N_CLASSES) {
            #pragma unroll
            for (int p = 0; p < 3; ++p) {
                int a = p * 256 + lane * 4;
                f32x4 wk = *reinterpret_cast<const f32x4*>(W  + (size_t)l * A_DIM + a);
                f32x4 cv = *reinterpret_cast<const f32x4*>(CV + (size_t)l * A_DIM + a);
                bf16x4 u, v;
                #pragma unroll
                for (int j = 0; j < 4; ++j) {
                    u[j] = (__bf16)cv[j];
                    v[j] = (__bf16)(-2.0f * wk[j] * cv[j]);
                }
                *reinterpret_cast<bf16x4*>(UVc + (size_t)l * K_DIM + a)         = u;
                *reinterpret_cast<bf16x4*>(UVc + (size_t)l * K_DIM + A_DIM + a) = v;
            }
        } else {
            #pragma unroll
            for (int p = 0; p < 6; ++p)
                *reinterpret_cast<bf16x4*>(UVc + (size_t)l * K_DIM + p * 256 + lane * 4) = z;
        }
    } else {
        int c = gw - C_PAD;
        if (c < N_CLASSES) {
            #pragma unroll
            for (int p = 0; p < 3; ++p) {
                int a = p * 256 + lane * 4;
                f32x4 w = *reinterpret_cast<const f32x4*>(W + (size_t)c * A_DIM + a);
                bf16x4 sq, li;
                #pragma unroll
                for (int j = 0; j < 4; ++j) { sq[j] = (__bf16)(w[j] * w[j]); li[j] = (__bf16)w[j]; }
                *reinterpret_cast<bf16x4*>(Wcat + (size_t)c * K_DIM + a)         = sq;
                *reinterpret_cast<bf16x4*>(Wcat + (size_t)c * K_DIM + A_DIM + a) = li;
            }
        } else {
            #pragma unroll
            for (int p = 0; p < 6; ++p)
                *reinterpret_cast<bf16x4*>(Wcat + (size_t)c * K_DIM + p * 256 + lane * 4) = z;
        }
    }
}

// ---- G-GEMM: G[l][c] = sum_k UVc[l,k]*Wcat[c,k]   (1024 x 1024 x 1536) -----
// 64x64 tile, 256 thr (4 waves in 2x2, each 32x32), grid 256 = 1 tile/CU,
// 3 blocks/CU resident (48 KB LDS). Same verified BK=64 swizzle + 3-stage
// counted-vmcnt phase discipline as R6 (4 loads/thread/tile -> vmcnt(4)).
__global__ __launch_bounds__(256, 3) void gemm_g(
        const __bf16* __restrict__ UVc, const __bf16* __restrict__ Wcat,
        __bf16* __restrict__ G) {
    __shared__ __align__(16) __bf16 As[3][BT * BK];   // 3 x 8 KB
    __shared__ __align__(16) __bf16 Bs[3][BT * BK];   // 3 x 8 KB
    int tid  = threadIdx.x;
    int lane = tid & 63;
    int wave = tid >> 6;
    // XCD-chunked bijective swizzle: 256 blocks, 8 XCDs, 32 blocks/XCD.
    int wgid = (blockIdx.x & 7) * 32 + (blockIdx.x >> 3);
    int rowBase = (wgid >> 4) * BT;      // 16 row tiles
    int colBase = (wgid & 15) * BT;      // 16 col tiles
    int wr = wave >> 1;                  // 2x2 wave grid, each wave 32x32
    int wc = wave & 1;

    f32x4 acc[2][2];
    #pragma unroll
    for (int m = 0; m < 2; ++m)
        #pragma unroll
        for (int n = 0; n < 2; ++n)
            acc[m][n] = (f32x4){0.f, 0.f, 0.f, 0.f};

    // stage: 64x64 tile = 512 16B-chunks; 256 thr -> 2 loads/thread/matrix.
    // LDS dest LINEAR; swizzle in GLOBAL source chunk index: cch ^ (row&7).
    auto stageA = [&](int b, int k0) {
        #pragma unroll
        for (int i = 0; i < 2; ++i) {
            int lin  = i * 256 + tid;
            int row  = lin >> 3;             // 0..63
            int scch = (lin & 7) ^ (row & 7);
            int base = i * 256 + (tid & ~63);
            const __bf16* ga = UVc + (size_t)(rowBase + row) * K_DIM + k0 + scch * 8;
            __builtin_amdgcn_global_load_lds(
                (const __attribute__((address_space(1))) void*)ga,
                (__attribute__((address_space(3))) void*)((char*)&As[b][0] + (size_t)base * 16),
                16, 0, 0);
        }
    };
    auto stageB = [&](int b, int k0) {
        #pragma unroll
        for (int i = 0; i < 2; ++i) {
            int lin  = i * 256 + tid;
            int row  = lin >> 3;
            int scch = (lin & 7) ^ (row & 7);
            int base = i * 256 + (tid & ~63);
            const __bf16* gb = Wcat + (size_t)(colBase + row) * K_DIM + k0 + scch * 8;
            __builtin_amdgcn_global_load_lds(
                (const __attribute__((address_space(1))) void*)gb,
                (__attribute__((address_space(3))) void*)((char*)&Bs[b][0] + (size_t)base * 16),
                16, 0, 0);
        }
    };
    auto loadFrags = [&](int b, int kk, bf16x8* af, bf16x8* bf) {
        int swch = ((kk * 4 + (lane >> 4)) ^ (lane & 7)) * 8;   // verified R2/R6
        #pragma unroll
        for (int m = 0; m < 2; ++m) {
            int r = wr * 32 + m * 16 + (lane & 15);
            af[m] = *reinterpret_cast<const bf16x8*>(&As[b][r * BK + swch]);
        }
        #pragma unroll
        for (int n = 0; n < 2; ++n) {
            int c = wc * 32 + n * 16 + (lane & 15);
            bf[n] = *reinterpret_cast<const bf16x8*>(&Bs[b][c * BK + swch]);
        }
    };
    auto doMFMA = [&](bf16x8* af, bf16x8* bf) {
        __builtin_amdgcn_s_setprio(1);
        #pragma unroll
        for (int m = 0; m < 2; ++m)
            #pragma unroll
            for (int n = 0; n < 2; ++n)
                acc[m][n] = __builtin_amdgcn_mfma_f32_16x16x32_bf16(
                    af[m], bf[n], acc[m][n], 0, 0, 0);
        __builtin_amdgcn_s_setprio(0);
    };

    stageA(0, 0);        stageB(0, 0);
    stageA(1, BK);       stageB(1, BK);
    WAIT_VM(4);                          // tile 0 landed; tile 1 in flight
    __builtin_amdgcn_s_barrier();

    for (int kt = 0; kt < NT; ++kt) {
        int bR = kt % 3;
        int bS = (kt + 2) % 3;
        bool st = (kt + 2) < NT;
        int k2 = (kt + 2) * BK;
        bf16x8 af[2], bf[2];
        // ---- phase 0 (kk=0)
        loadFrags(bR, 0, af, bf);
        if (st) stageA(bS, k2);
        __builtin_amdgcn_s_barrier();
        WAIT_LGKM0;
        doMFMA(af, bf);
        __builtin_amdgcn_s_barrier();
        // ---- phase 1 (kk=1)
        loadFrags(bR, 1, af, bf);
        if (st) stageB(bS, k2);
        // in flight: 4 (tile kt+1) + 4 (tile kt+2) -> keep 4 => kt+1 landed
        if (st) { WAIT_VM(4); } else { WAIT_VM(0); }
        __builtin_amdgcn_s_barrier();
        WAIT_LGKM0;
        doMFMA(af, bf);
        __builtin_amdgcn_s_barrier();
    }

    // epilogue: C/D layout col=lane&15, row=(lane>>4)*4+j [verified m89/m91]
    int lr = (lane >> 4) * 4;
    int lc = lane & 15;
    #pragma unroll
    for (int m = 0; m < 2; ++m) {
        #pragma unroll
        for (int n = 0; n < 2; ++n) {
            int gr0 = rowBase + wr * 32 + m * 16 + lr;
            int gc  = colBase + wc * 32 + n * 16 + lc;
            #pragma unroll
            for (int j = 0; j < 4; ++j)
                G[(size_t)(gr0 + j) * C_PAD + gc] = (__bf16)acc[m][n][j];
        }
    }
}

// ------- fused: aug = logits + h*G[label]; log-softmax NLL at label ---------
// one wave per sample row (4/block); G row (2 KB) comes from L2 (G = 2 MB).
__global__ void softmax_loss(const __bf16* __restrict__ G,
                             const float* __restrict__ logits,
                             const float* __restrict__ ratiop,
                             const int* __restrict__ labels,
                             float* __restrict__ rowloss) {
    int tid  = threadIdx.x;
    int lane = tid & 63;
    int wv   = tid >> 6;
    int gw   = blockIdx.x * 4 + wv;
    float h  = 0.5f * ratiop[0];
    int  lab = labels[gw];               // wave-uniform -> scalar load
    const __bf16* rowp = G + (size_t)lab * C_PAD;
    const float*  lrow = logits + (size_t)gw * N_CLASSES;

    bf16x8 v0 = *reinterpret_cast<const bf16x8*>(rowp + lane * 8);
    bf16x8 v1 = *reinterpret_cast<const bf16x8*>(rowp + 512 + lane * 8);
    f32x4 l0a = *reinterpret_cast<const f32x4*>(lrow + lane * 8);
    f32x4 l0b = *reinterpret_cast<const f32x4*>(lrow + lane * 8 + 4);
    f32x4 l1a = {0.f,0.f,0.f,0.f}, l1b = {0.f,0.f,0.f,0.f};
    if (lane < 61) {                 // cols 512+lane*8..+7 < 1000 iff lane < 61
        l1a = *reinterpret_cast<const f32x4*>(lrow + 512 + lane * 8);
        l1b = *reinterpret_cast<const f32x4*>(lrow + 512 + lane * 8 + 4);
    }
    float f[16];
    #pragma unroll
    for (int j = 0; j < 4; ++j) {
        f[j]     = l0a[j] + h * (float)v0[j];
        f[4 + j] = l0b[j] + h * (float)v0[4 + j];
    }
    #pragma unroll
    for (int j = 0; j < 4; ++j) {
        f[8 + j]  = (lane < 61) ? l1a[j] + h * (float)v1[j]     : -1e30f;
        f[12 + j] = (lane < 61) ? l1b[j] + h * (float)v1[4 + j] : -1e30f;
    }
    float m = -1e30f;
    #pragma unroll
    for (int j = 0; j < 16; ++j) m = fmaxf(m, f[j]);
    #pragma unroll
    for (int s = 32; s > 0; s >>= 1) m = fmaxf(m, __shfl_xor(m, s));
    float sum = 0.f;
    #pragma unroll
    for (int j = 0; j < 16; ++j) sum += __expf(f[j] - m);
    #pragma unroll
    for (int s = 32; s > 0; s >>= 1) sum += __shfl_xor(sum, s);
    if (lane == 0) {
        float tv = lrow[lab] + h * (float)rowp[lab];
        rowloss[gw] = logf(sum) + m - tv;
    }
}

// ---------------- deterministic final mean (fixed-order, no atomics) --------
__global__ void finalize(const float* __restrict__ rowloss, float* __restrict__ out) {
    int tid = threadIdx.x;
    float part = 0.f;
    #pragma unroll
    for (int i = 0; i < 8; ++i) part += rowloss[i * 1024 + tid];
    #pragma unroll
    for (int s = 32; s > 0; s >>= 1) part += __shfl_xor(part, s);
    __shared__ float tmp[16];
    int lane = tid & 63, wv = tid >> 6;
    if (lane == 0) tmp[wv] = part;
    __syncthreads();
    if (tid == 0) {
        float sum = 0.f;
        #pragma unroll
        for (int w = 0; w < 16; ++w) sum += tmp[w];
        out[0] = sum / (float)N_SAMPLES;
    }
}

extern "C" void kernel_launch(void* const* d_in, const int* in_sizes, int n_in,
                              void* d_out, int out_size, void* d_ws, size_t ws_size,
                              hipStream_t stream) {
    const float* W      = (const float*)d_in[0];   // fc_weight [C, A]
    // d_in[1] = features [N, A] — unused by the reference math
    const float* logits = (const float*)d_in[2];   // [N, C]
    const int*   labels = (const int*)d_in[3];     // [N]
    const float* ratio  = (const float*)d_in[4];   // scalar
    const float* CV     = (const float*)d_in[5];   // cv_matrix [C, A]
    // d_in[6] = manner — unused

    // workspace layout (bytes), total ~8.4 MB
    char* ws = (char*)d_ws;
    __bf16* Wcat    = (__bf16*)(ws + 0);            // 3,145,728 B  [1024][1536] bf16
    __bf16* UVc     = (__bf16*)(ws + 3145728);      // 3,145,728 B  [1024][1536] bf16
    __bf16* G       = (__bf16*)(ws + 6291456);      // 2,097,152 B  [1024][1024] bf16
    float*  rowloss = (float*) (ws + 8388608);      //    32,768 B  [8192] f32

    prep<<<2 * C_PAD / 4, 256, 0, stream>>>(W, CV, UVc, Wcat);
    gemm_g<<<256, 256, 0, stream>>>(UVc, Wcat, G);
    softmax_loss<<<N_SAMPLES / 4, 256, 0, stream>>>(G, logits, ratio, labels, rowloss);
    finalize<<<1, 1024, 0, stream>>>(rowloss, (float*)d_out);
}

// Round 9
// 38.060 us; speedup vs baseline: 1.8235x; 1.0356x over previous
//
#include <hip/hip_runtime.h>
#include <cstdint>
#include <cstddef>

// Problem constants (reference: N=8192, C=1000, A=768)
// KEY IDENTITY: sigma2[n,c] = ratio * sum_a (W[c,a]-W[l,a])^2 cv[l,a] depends
// on n only through l = labels[n]. Compute G[l,c] once (1024^2) and gather.
#define N_SAMPLES 8192
#define N_CLASSES 1000
#define C_PAD     1024
#define A_DIM     768
#define K_DIM     1536   // 2*A  (concatenated [u ; v] / [W^2 ; W])
#define BT 64            // G-GEMM tile (64x64)
#define BK 64
#define NT (K_DIM / BK)  // 24 K-steps

typedef __attribute__((ext_vector_type(8))) __bf16 bf16x8;
typedef __attribute__((ext_vector_type(4))) __bf16 bf16x4;
typedef __attribute__((ext_vector_type(4))) float  f32x4;

#define WAIT_VM(N) do { asm volatile("s_waitcnt vmcnt(" #N ")" ::: "memory"); \
                        __builtin_amdgcn_sched_barrier(0); } while (0)
#define WAIT_LGKM0 do { asm volatile("s_waitcnt lgkmcnt(0)" ::: "memory"); \
                        __builtin_amdgcn_sched_barrier(0); } while (0)

// ---- prep: waves 0..1023 build UVc rows; waves 1024..2047 build Wcat rows --
// UVc[l][a] = cv[l,a] ; UVc[l][768+a] = -2*W[l,a]*cv[l,a]  (t3 term is a
// per-row constant shift -> cancels exactly in log-softmax; dropped).
// Wcat[c][a] = W[c,a]^2 ; Wcat[c][768+a] = W[c,a].  Pad rows zeroed.
__global__ void prep(const float* __restrict__ W, const float* __restrict__ CV,
                     __bf16* __restrict__ UVc, __bf16* __restrict__ Wcat) {
    int gw   = (blockIdx.x * blockDim.x + threadIdx.x) >> 6;
    int lane = threadIdx.x & 63;
    bf16x4 z = {(__bf16)0.f, (__bf16)0.f, (__bf16)0.f, (__bf16)0.f};
    if (gw < C_PAD) {
        int l = gw;
        if (l < N_CLASSES) {
            #pragma unroll
            for (int p = 0; p < 3; ++p) {
                int a = p * 256 + lane * 4;
                f32x4 wk = *reinterpret_cast<const f32x4*>(W  + (size_t)l * A_DIM + a);
                f32x4 cv = *reinterpret_cast<const f32x4*>(CV + (size_t)l * A_DIM + a);
                bf16x4 u, v;
                #pragma unroll
                for (int j = 0; j < 4; ++j) {
                    u[j] = (__bf16)cv[j];
                    v[j] = (__bf16)(-2.0f * wk[j] * cv[j]);
                }
                *reinterpret_cast<bf16x4*>(UVc + (size_t)l * K_DIM + a)         = u;
                *reinterpret_cast<bf16x4*>(UVc + (size_t)l * K_DIM + A_DIM + a) = v;
            }
        } else {
            #pragma unroll
            for (int p = 0; p < 6; ++p)
                *reinterpret_cast<bf16x4*>(UVc + (size_t)l * K_DIM + p * 256 + lane * 4) = z;
        }
    } else {
        int c = gw - C_PAD;
        if (c < N_CLASSES) {
            #pragma unroll
            for (int p = 0; p < 3; ++p) {
                int a = p * 256 + lane * 4;
                f32x4 w = *reinterpret_cast<const f32x4*>(W + (size_t)c * A_DIM + a);
                bf16x4 sq, li;
                #pragma unroll
                for (int j = 0; j < 4; ++j) { sq[j] = (__bf16)(w[j] * w[j]); li[j] = (__bf16)w[j]; }
                *reinterpret_cast<bf16x4*>(Wcat + (size_t)c * K_DIM + a)         = sq;
                *reinterpret_cast<bf16x4*>(Wcat + (size_t)c * K_DIM + A_DIM + a) = li;
            }
        } else {
            #pragma unroll
            for (int p = 0; p < 6; ++p)
                *reinterpret_cast<bf16x4*>(Wcat + (size_t)c * K_DIM + p * 256 + lane * 4) = z;
        }
    }
}

// ---- G-GEMM: G[l][c] = sum_k UVc[l,k]*Wcat[c,k]   (1024 x 1024 x 1536) -----
// 64x64 tile, 512 thr (8 waves in 4x2, each 16x32 -> 2 waves/SIMD), grid 256.
// 3-stage pipeline, m201 phase discipline, counted vmcnt (1 load/thread per
// matrix per tile -> boundary vmcnt(2)), verified BK=64 XOR swizzle.
__global__ __launch_bounds__(512, 2) void gemm_g(
        const __bf16* __restrict__ UVc, const __bf16* __restrict__ Wcat,
        __bf16* __restrict__ G) {
    __shared__ __align__(16) __bf16 As[3][BT * BK];   // 3 x 8 KB
    __shared__ __align__(16) __bf16 Bs[3][BT * BK];   // 3 x 8 KB
    int tid  = threadIdx.x;
    int lane = tid & 63;
    int wave = tid >> 6;
    // XCD-chunked bijective swizzle: 256 blocks, 8 XCDs, 32 blocks/XCD.
    int wgid = (blockIdx.x & 7) * 32 + (blockIdx.x >> 3);
    int rowBase = (wgid >> 4) * BT;      // 16 row tiles
    int colBase = (wgid & 15) * BT;      // 16 col tiles
    int wr = wave >> 1;                  // 4x2 wave grid, each wave 16x32
    int wc = wave & 1;

    f32x4 acc[2];                        // [n], n = 0..1 (cols), 1 row-frag
    acc[0] = (f32x4){0.f, 0.f, 0.f, 0.f};
    acc[1] = (f32x4){0.f, 0.f, 0.f, 0.f};

    // stage: 64x64 tile = 512 16B-chunks; 512 thr -> 1 load/thread/matrix.
    // LDS dest LINEAR; swizzle in GLOBAL source chunk index: cch ^ (row&7).
    auto stageA = [&](int b, int k0) {
        int row  = tid >> 3;             // 0..63
        int scch = (tid & 7) ^ (row & 7);
        int base = tid & ~63;
        const __bf16* ga = UVc + (size_t)(rowBase + row) * K_DIM + k0 + scch * 8;
        __builtin_amdgcn_global_load_lds(
            (const __attribute__((address_space(1))) void*)ga,
            (__attribute__((address_space(3))) void*)((char*)&As[b][0] + (size_t)base * 16),
            16, 0, 0);
    };
    auto stageB = [&](int b, int k0) {
        int row  = tid >> 3;
        int scch = (tid & 7) ^ (row & 7);
        int base = tid & ~63;
        const __bf16* gb = Wcat + (size_t)(colBase + row) * K_DIM + k0 + scch * 8;
        __builtin_amdgcn_global_load_lds(
            (const __attribute__((address_space(1))) void*)gb,
            (__attribute__((address_space(3))) void*)((char*)&Bs[b][0] + (size_t)base * 16),
            16, 0, 0);
    };
    auto loadFrags = [&](int b, int kk, bf16x8* af, bf16x8* bf) {
        int swch = ((kk * 4 + (lane >> 4)) ^ (lane & 7)) * 8;   // verified R2/R6
        int r = wr * 16 + (lane & 15);
        af[0] = *reinterpret_cast<const bf16x8*>(&As[b][r * BK + swch]);
        #pragma unroll
        for (int n = 0; n < 2; ++n) {
            int c = wc * 32 + n * 16 + (lane & 15);
            bf[n] = *reinterpret_cast<const bf16x8*>(&Bs[b][c * BK + swch]);
        }
    };
    auto doMFMA = [&](bf16x8* af, bf16x8* bf) {
        __builtin_amdgcn_s_setprio(1);
        #pragma unroll
        for (int n = 0; n < 2; ++n)
            acc[n] = __builtin_amdgcn_mfma_f32_16x16x32_bf16(
                af[0], bf[n], acc[n], 0, 0, 0);
        __builtin_amdgcn_s_setprio(0);
    };

    stageA(0, 0);        stageB(0, 0);
    stageA(1, BK);       stageB(1, BK);
    WAIT_VM(2);                          // tile 0 landed; tile 1 (2) in flight
    __builtin_amdgcn_s_barrier();

    for (int kt = 0; kt < NT; ++kt) {
        int bR = kt % 3;
        int bS = (kt + 2) % 3;
        bool st = (kt + 2) < NT;
        int k2 = (kt + 2) * BK;
        bf16x8 af[1], bf[2];
        // ---- phase 0 (kk=0)
        loadFrags(bR, 0, af, bf);
        if (st) stageA(bS, k2);
        __builtin_amdgcn_s_barrier();
        WAIT_LGKM0;
        doMFMA(af, bf);
        __builtin_amdgcn_s_barrier();
        // ---- phase 1 (kk=1)
        loadFrags(bR, 1, af, bf);
        if (st) stageB(bS, k2);
        // in flight: 2 (tile kt+1) + 2 (tile kt+2) -> keep 2 => kt+1 landed;
        // at kt=NT-2 no new issues -> drain to 0 so tile NT-1 is landed.
        if (st) { WAIT_VM(2); } else { WAIT_VM(0); }
        __builtin_amdgcn_s_barrier();
        WAIT_LGKM0;
        doMFMA(af, bf);
        __builtin_amdgcn_s_barrier();
    }

    // epilogue: C/D layout col=lane&15, row=(lane>>4)*4+j [verified m89/m91]
    int lr = (lane >> 4) * 4;
    int lc = lane & 15;
    #pragma unroll
    for (int n = 0; n < 2; ++n) {
        int gr0 = rowBase + wr * 16 + lr;
        int gc  = colBase + wc * 32 + n * 16 + lc;
        #pragma unroll
        for (int j = 0; j < 4; ++j)
            G[(size_t)(gr0 + j) * C_PAD + gc] = (__bf16)acc[n][j];
    }
}

// ------- fused: aug = logits + h*G[label]; log-softmax NLL at label ---------
// one wave per sample row (4/block); G row (2 KB) from L2/L3; logits read
// once -> non-temporal so they don't evict G from L2.
__global__ void softmax_loss(const __bf16* __restrict__ G,
                             const float* __restrict__ logits,
                             const float* __restrict__ ratiop,
                             const int* __restrict__ labels,
                             float* __restrict__ rowloss) {
    int tid  = threadIdx.x;
    int lane = tid & 63;
    int wv   = tid >> 6;
    int gw   = blockIdx.x * 4 + wv;
    float h  = 0.5f * ratiop[0];
    int  lab = labels[gw];               // wave-uniform -> scalar load
    const __bf16* rowp = G + (size_t)lab * C_PAD;
    const float*  lrow = logits + (size_t)gw * N_CLASSES;

    bf16x8 v0 = *reinterpret_cast<const bf16x8*>(rowp + lane * 8);
    bf16x8 v1 = *reinterpret_cast<const bf16x8*>(rowp + 512 + lane * 8);
    f32x4 l0a = __builtin_nontemporal_load(reinterpret_cast<const f32x4*>(lrow + lane * 8));
    f32x4 l0b = __builtin_nontemporal_load(reinterpret_cast<const f32x4*>(lrow + lane * 8 + 4));
    f32x4 l1a = {0.f,0.f,0.f,0.f}, l1b = {0.f,0.f,0.f,0.f};
    if (lane < 61) {                 // cols 512+lane*8..+7 < 1000 iff lane < 61
        l1a = __builtin_nontemporal_load(reinterpret_cast<const f32x4*>(lrow + 512 + lane * 8));
        l1b = __builtin_nontemporal_load(reinterpret_cast<const f32x4*>(lrow + 512 + lane * 8 + 4));
    }
    float f[16];
    #pragma unroll
    for (int j = 0; j < 4; ++j) {
        f[j]     = l0a[j] + h * (float)v0[j];
        f[4 + j] = l0b[j] + h * (float)v0[4 + j];
    }
    #pragma unroll
    for (int j = 0; j < 4; ++j) {
        f[8 + j]  = (lane < 61) ? l1a[j] + h * (float)v1[j]     : -1e30f;
        f[12 + j] = (lane < 61) ? l1b[j] + h * (float)v1[4 + j] : -1e30f;
    }
    float m = -1e30f;
    #pragma unroll
    for (int j = 0; j < 16; ++j) m = fmaxf(m, f[j]);
    #pragma unroll
    for (int s = 32; s > 0; s >>= 1) m = fmaxf(m, __shfl_xor(m, s));
    float sum = 0.f;
    #pragma unroll
    for (int j = 0; j < 16; ++j) sum += __expf(f[j] - m);
    #pragma unroll
    for (int s = 32; s > 0; s >>= 1) sum += __shfl_xor(sum, s);
    if (lane == 0) {
        float tv = lrow[lab] + h * (float)rowp[lab];
        rowloss[gw] = logf(sum) + m - tv;
    }
}

// ---------------- deterministic final mean (fixed-order, no atomics) --------
__global__ void finalize(const float* __restrict__ rowloss, float* __restrict__ out) {
    int tid = threadIdx.x;
    float part = 0.f;
    #pragma unroll
    for (int i = 0; i < 8; ++i) part += rowloss[i * 1024 + tid];
    #pragma unroll
    for (int s = 32; s > 0; s >>= 1) part += __shfl_xor(part, s);
    __shared__ float tmp[16];
    int lane = tid & 63, wv = tid >> 6;
    if (lane == 0) tmp[wv] = part;
    __syncthreads();
    if (tid == 0) {
        float sum = 0.f;
        #pragma unroll
        for (int w = 0; w < 16; ++w) sum += tmp[w];
        out[0] = sum / (float)N_SAMPLES;
    }
}

extern "C" void kernel_launch(void* const* d_in, const int* in_sizes, int n_in,
                              void* d_out, int out_size, void* d_ws, size_t ws_size,
                              hipStream_t stream) {
    const float* W      = (const float*)d_in[0];   // fc_weight [C, A]
    // d_in[1] = features [N, A] — unused by the reference math
    const float* logits = (const float*)d_in[2];   // [N, C]
    const int*   labels = (const int*)d_in[3];     // [N]
    const float* ratio  = (const float*)d_in[4];   // scalar
    const float* CV     = (const float*)d_in[5];   // cv_matrix [C, A]
    // d_in[6] = manner — unused

    // workspace layout (bytes), total ~8.4 MB
    char* ws = (char*)d_ws;
    __bf16* Wcat    = (__bf16*)(ws + 0);            // 3,145,728 B  [1024][1536] bf16
    __bf16* UVc     = (__bf16*)(ws + 3145728);      // 3,145,728 B  [1024][1536] bf16
    __bf16* G       = (__bf16*)(ws + 6291456);      // 2,097,152 B  [1024][1024] bf16
    float*  rowloss = (float*) (ws + 8388608);      //    32,768 B  [8192] f32

    prep<<<2 * C_PAD / 4, 256, 0, stream>>>(W, CV, UVc, Wcat);
    gemm_g<<<256, 512, 0, stream>>>(UVc, Wcat, G);
    softmax_loss<<<N_SAMPLES / 4, 256, 0, stream>>>(G, logits, ratio, labels, rowloss);
    finalize<<<1, 1024, 0, stream>>>(rowloss, (float*)d_out);
}